// Round 5
// baseline (64.619 us; speedup 1.0000x reference)
//
#include <hip/hip_runtime.h>

#define NNODES 128
#define BATCH  32768
#define BLOCK  256                          // 4 waves
#define ROWS_PER_CHUNK 8                    // 4 waves x 2 rows
#define NCHUNKS (BATCH / ROWS_PER_CHUNK)    // 4096
#define GRID   1024                         // 4 chunks/block

__device__ __forceinline__ float sigmoidf_(float z) {
    return 1.0f / (1.0f + __expf(-z));
}

__device__ __forceinline__ float clipf_(float v) {
    return fminf(fmaxf(v, -100.0f), 100.0f);
}

__device__ __forceinline__ unsigned short bf16_(float f) {
    unsigned u = __float_as_uint(f);
    return (unsigned short)((u + 0x8000u) >> 16);
}

// Per-node epilogue: 8 clipped states + node_input + params -> 8 derivatives.
__device__ __forceinline__ void node_update(const float* xs8, float ni,
                                            const float* gi, const float* invTi,
                                            float sci, float Ri, float* f8) {
    float S0 = sigmoidf_(Ri * xs8[0]) - 0.5f;
    float S2 = sigmoidf_(Ri * xs8[2]) - 0.5f;
    float S4 = sigmoidf_(Ri * xs8[4]) - 0.5f;
    float S6 = sigmoidf_(Ri * xs8[6]) - 0.5f;
    float u1 = ni - gi[0] * S0 - gi[1] * S2 - gi[2]  * S4;
    float u3 = ni + gi[7] * S0 - gi[6] * S2 - gi[11] * S4;
    float u5 = ni + gi[4] * S0 + gi[10] * S2 - gi[3] * S4 + gi[5] * S6;
    float u7 = ni - gi[8] * S4 - gi[9] * S6;
    f8[0] = sci * xs8[1];
    f8[1] = sci * (u1 - 2.0f * xs8[1] - xs8[0] * invTi[0]) * invTi[0];
    f8[2] = sci * xs8[3];
    f8[3] = sci * (u3 - 2.0f * xs8[3] - xs8[2] * invTi[1]) * invTi[1];
    f8[4] = sci * xs8[5];
    f8[5] = sci * (u5 - 2.0f * xs8[5] - xs8[4] * invTi[2]) * invTi[2];
    f8[6] = sci * xs8[7];
    f8[7] = sci * (u7 - 2.0f * xs8[7] - xs8[6] * invTi[3]) * invTi[3];
}

__global__ __launch_bounds__(BLOCK, 2)
void cmc_kernel(const float* __restrict__ x,
                const float* __restrict__ C,
                const float* __restrict__ G,
                const float* __restrict__ T,
                const float* __restrict__ adap,
                const float* __restrict__ R,
                float* __restrict__ out)
{
    // Tiled transposed connectivity, bf16, diag zeroed:
    //   record ct4[j4*64 + (p ^ j4)] (16B) holds, for node-pair p (nodes 2p,2p+1)
    //   and j in [4*j4, 4*j4+4):
    //     .x = {bf16 C[.][2p]   j=+0, j=+1}   (packed lo,hi)
    //     .y = {bf16 C[.][2p]   j=+2, j=+3}   -- wait: ct[j][i] = C[i][j]; ushorts
    //     .z/.w same for node 2p+1.
    //   The ^j4 slot swizzle makes BOTH staging writes and per-iter reads
    //   full-row permutations -> conflict-free. Read: ONE ds_read_b128/lane/j4.
    __shared__ uint4 ct4[32 * 64];              // 32 KB
    __shared__ float m_lds[4][2][NNODES];       //  4 KB (per-wave private)

    const int tid  = threadIdx.x;
    const int lane = tid & 63;
    const int w    = tid >> 6;            // wave 0..3
    const int nA   = 2 * lane;            // this lane's nodes: nA, nA+1

    // ---- stage ct once per block ----
    {
        const int j0 = (tid & 31) * 4;    // coalesced source reads (cols j0..j0+3)
        const int j4 = j0 >> 2;
        const int tb = tid >> 5;          // 0..7
        #pragma unroll
        for (int it = 0; it < 4; ++it) {
            const int i0 = (tb + it * 8) * 4;       // rows i0..i0+3
            float4 row[4];
            #pragma unroll
            for (int r = 0; r < 4; ++r)
                row[r] = *reinterpret_cast<const float4*>(C + (size_t)(i0 + r) * NNODES + j0);
            unsigned short t[4][4];
            #pragma unroll
            for (int r = 0; r < 4; ++r) {
                #pragma unroll
                for (int jj = 0; jj < 4; ++jj)
                    t[r][jj] = (i0 + r == j0 + jj) ? (unsigned short)0
                                                   : bf16_((&row[r].x)[jj]);
            }
            uint4 rec0, rec1;
            rec0.x = (unsigned)t[0][0] | ((unsigned)t[0][1] << 16);
            rec0.y = (unsigned)t[0][2] | ((unsigned)t[0][3] << 16);
            rec0.z = (unsigned)t[1][0] | ((unsigned)t[1][1] << 16);
            rec0.w = (unsigned)t[1][2] | ((unsigned)t[1][3] << 16);
            rec1.x = (unsigned)t[2][0] | ((unsigned)t[2][1] << 16);
            rec1.y = (unsigned)t[2][2] | ((unsigned)t[2][3] << 16);
            rec1.z = (unsigned)t[3][0] | ((unsigned)t[3][1] << 16);
            rec1.w = (unsigned)t[3][2] | ((unsigned)t[3][3] << 16);
            const int p0 = i0 >> 1;
            ct4[j4 * 64 + (p0 ^ j4)]       = rec0;
            ct4[j4 * 64 + ((p0 + 1) ^ j4)] = rec1;
        }
    }

    // ---- per-node params (2 nodes/lane) ----
    float g[2][12], invT[2][4], sc[2], Rr[2];
    #pragma unroll
    for (int i = 0; i < 2; ++i) {
        int n = nA + i;
        #pragma unroll
        for (int k = 0; k < 12; ++k) g[i][k] = G[n * 12 + k];
        #pragma unroll
        for (int k = 0; k < 4; ++k) invT[i][k] = 1.0f / T[n * 4 + k];
        sc[i] = 0.1f * sigmoidf_(adap[n]);
        Rr[i] = R[n];
    }

    __syncthreads();   // ct4 visible; ONLY barrier in the kernel

    for (int chunk = blockIdx.x; chunk < NCHUNKS; chunk += GRID) {
        const int r0 = chunk * ROWS_PER_CHUNK + 2 * w;   // wave's rows: r0, r0+1

        // ---- load + clip x: 2 rows, this lane's 16 columns (own nodes) ----
        float xv[2][16];
        {
            const float4* p0 = reinterpret_cast<const float4*>(x + (size_t)r0 * 1024 + lane * 16);
            const float4* p1 = reinterpret_cast<const float4*>(x + (size_t)(r0 + 1) * 1024 + lane * 16);
            #pragma unroll
            for (int q = 0; q < 4; ++q) {
                float4 v = p0[q];
                xv[0][q * 4 + 0] = clipf_(v.x); xv[0][q * 4 + 1] = clipf_(v.y);
                xv[0][q * 4 + 2] = clipf_(v.z); xv[0][q * 4 + 3] = clipf_(v.w);
            }
            #pragma unroll
            for (int q = 0; q < 4; ++q) {
                float4 v = p1[q];
                xv[1][q * 4 + 0] = clipf_(v.x); xv[1][q * 4 + 1] = clipf_(v.y);
                xv[1][q * 4 + 2] = clipf_(v.z); xv[1][q * 4 + 3] = clipf_(v.w);
            }
        }

        // ---- node means (lane-local) -> per-wave-private LDS row ----
        #pragma unroll
        for (int rr = 0; rr < 2; ++rr) {
            float s0 = 0.0f, s1 = 0.0f;
            #pragma unroll
            for (int k = 0; k < 8; ++k) { s0 += xv[rr][k]; s1 += xv[rr][8 + k]; }
            float2 mv = make_float2(s0 * 0.125f, s1 * 0.125f);
            *reinterpret_cast<float2*>(&m_lds[w][rr][nA]) = mv;
        }
        // same-wave write->read: ordered by lgkmcnt, no barrier needed

        // ---- node_input: acc[rr][i] = sum_j m[rr][j] * Ct[j][nA+i] ----
        float acc00 = 0.f, acc01 = 0.f, acc10 = 0.f, acc11 = 0.f;
        #pragma unroll 4
        for (int j4 = 0; j4 < 32; ++j4) {
            float4 mA = *reinterpret_cast<const float4*>(&m_lds[w][0][j4 * 4]);  // broadcast
            float4 mB = *reinterpret_cast<const float4*>(&m_lds[w][1][j4 * 4]);  // broadcast
            uint4 cu = ct4[j4 * 64 + (lane ^ j4)];   // one b128, conflict-free perm
            float ce0 = __uint_as_float(cu.x << 16);
            float ce1 = __uint_as_float(cu.x & 0xffff0000u);
            float ce2 = __uint_as_float(cu.y << 16);
            float ce3 = __uint_as_float(cu.y & 0xffff0000u);
            float co0 = __uint_as_float(cu.z << 16);
            float co1 = __uint_as_float(cu.z & 0xffff0000u);
            float co2 = __uint_as_float(cu.w << 16);
            float co3 = __uint_as_float(cu.w & 0xffff0000u);
            acc00 = fmaf(mA.x, ce0, acc00); acc00 = fmaf(mA.y, ce1, acc00);
            acc00 = fmaf(mA.z, ce2, acc00); acc00 = fmaf(mA.w, ce3, acc00);
            acc01 = fmaf(mA.x, co0, acc01); acc01 = fmaf(mA.y, co1, acc01);
            acc01 = fmaf(mA.z, co2, acc01); acc01 = fmaf(mA.w, co3, acc01);
            acc10 = fmaf(mB.x, ce0, acc10); acc10 = fmaf(mB.y, ce1, acc10);
            acc10 = fmaf(mB.z, ce2, acc10); acc10 = fmaf(mB.w, ce3, acc10);
            acc11 = fmaf(mB.x, co0, acc11); acc11 = fmaf(mB.y, co1, acc11);
            acc11 = fmaf(mB.z, co2, acc11); acc11 = fmaf(mB.w, co3, acc11);
        }

        // ---- epilogue + store: 2 rows x 2 nodes ----
        {
            float* o0 = out + (size_t)r0 * 1024 + lane * 16;
            float* o1 = out + (size_t)(r0 + 1) * 1024 + lane * 16;
            float f8[8];
            node_update(&xv[0][0], acc00, g[0], invT[0], sc[0], Rr[0], f8);
            *reinterpret_cast<float4*>(o0)      = make_float4(f8[0], f8[1], f8[2], f8[3]);
            *reinterpret_cast<float4*>(o0 + 4)  = make_float4(f8[4], f8[5], f8[6], f8[7]);
            node_update(&xv[0][8], acc01, g[1], invT[1], sc[1], Rr[1], f8);
            *reinterpret_cast<float4*>(o0 + 8)  = make_float4(f8[0], f8[1], f8[2], f8[3]);
            *reinterpret_cast<float4*>(o0 + 12) = make_float4(f8[4], f8[5], f8[6], f8[7]);
            node_update(&xv[1][0], acc10, g[0], invT[0], sc[0], Rr[0], f8);
            *reinterpret_cast<float4*>(o1)      = make_float4(f8[0], f8[1], f8[2], f8[3]);
            *reinterpret_cast<float4*>(o1 + 4)  = make_float4(f8[4], f8[5], f8[6], f8[7]);
            node_update(&xv[1][8], acc11, g[1], invT[1], sc[1], Rr[1], f8);
            *reinterpret_cast<float4*>(o1 + 8)  = make_float4(f8[0], f8[1], f8[2], f8[3]);
            *reinterpret_cast<float4*>(o1 + 12) = make_float4(f8[4], f8[5], f8[6], f8[7]);
        }
        // m_lds[w] is wave-private: WAR across chunks is same-wave, safe
    }
}

extern "C" void kernel_launch(void* const* d_in, const int* in_sizes, int n_in,
                              void* d_out, int out_size, void* d_ws, size_t ws_size,
                              hipStream_t stream) {
    // setup_inputs order: t, x, node_connectivity, G, T, adaptation, R
    const float* x    = (const float*)d_in[1];
    const float* C    = (const float*)d_in[2];
    const float* G    = (const float*)d_in[3];
    const float* T    = (const float*)d_in[4];
    const float* adap = (const float*)d_in[5];
    const float* R    = (const float*)d_in[6];
    float* out        = (float*)d_out;

    hipLaunchKernelGGL(cmc_kernel, dim3(GRID), dim3(BLOCK), 0, stream,
                       x, C, G, T, adap, R, out);
}